// Round 1
// baseline (1896.867 us; speedup 1.0000x reference)
//
#include <hip/hip_runtime.h>
#include <hip/hip_bf16.h>

#define C2 340
#define HID 170
#define NB 4
#define HGT 256
#define WID 256
#define HW (HGT*WID)

typedef unsigned short u16;
typedef unsigned int u32;

__device__ __forceinline__ float bf2f(u16 u) {
  union { u32 i; float f; } v; v.i = ((u32)u) << 16; return v.f;
}
__device__ __forceinline__ u16 f2bf(float f) {
  union { float f; u32 i; } v; v.f = f;
  u32 x = v.i;
  return (u16)((x + 0x7fffu + ((x >> 16) & 1u)) >> 16);
}

__device__ const float COSTAB[8] = {1.f, 0.70710678118654752f, 0.f, -0.70710678118654752f,
                                    -1.f, -0.70710678118654752f, 0.f, 0.70710678118654752f};

// ---------------- K1: project_in (64 -> 340), write bf16 mid ----------------
__global__ __launch_bounds__(256) void k_projin(const float* __restrict__ x,
                                                const float* __restrict__ w_in,
                                                u16* __restrict__ mid) {
  __shared__ float xs[64 * WID];            // 64 KB: one (b,h) row, all 64 in-channels
  const int bx = blockIdx.x;                // b*256 + h
  const int b = bx >> 8, h = bx & 255;
  const float* xp = x + ((size_t)b * 64) * HW + (size_t)h * WID;
  for (int i = threadIdx.x; i < 64 * (WID/4); i += 256) {
    const int c = i >> 6, w4 = i & 63;
    ((float4*)xs)[c * (WID/4) + w4] = ((const float4*)(xp + (size_t)c * HW))[w4];
  }
  __syncthreads();
  const int p = threadIdx.x;                // pixel w
  for (int ob = 0; ob < 85; ++ob) {         // 85 * 4 = 340 out channels
    const int o0 = ob * 4;
    float a0 = 0.f, a1 = 0.f, a2 = 0.f, a3 = 0.f;
    #pragma unroll
    for (int c4 = 0; c4 < 16; ++c4) {
      const float x0 = xs[(c4*4+0)*WID + p];
      const float x1 = xs[(c4*4+1)*WID + p];
      const float x2 = xs[(c4*4+2)*WID + p];
      const float x3 = xs[(c4*4+3)*WID + p];
      const float4 w0 = *(const float4*)(w_in + (o0+0)*64 + c4*4);
      const float4 w1 = *(const float4*)(w_in + (o0+1)*64 + c4*4);
      const float4 w2 = *(const float4*)(w_in + (o0+2)*64 + c4*4);
      const float4 w3 = *(const float4*)(w_in + (o0+3)*64 + c4*4);
      a0 += w0.x*x0 + w0.y*x1 + w0.z*x2 + w0.w*x3;
      a1 += w1.x*x0 + w1.y*x1 + w1.z*x2 + w1.w*x3;
      a2 += w2.x*x0 + w2.y*x1 + w2.z*x2 + w2.w*x3;
      a3 += w3.x*x0 + w3.y*x1 + w3.z*x2 + w3.w*x3;
    }
    u16* mp = mid + ((size_t)(b*C2 + o0)) * HW + (size_t)h * WID + p;
    mp[0]            = f2bf(a0);
    mp[(size_t)HW]   = f2bf(a1);
    mp[(size_t)2*HW] = f2bf(a2);
    mp[(size_t)3*HW] = f2bf(a3);
  }
}

// ------- K2: per-channel 8x8 circular conv (== rfft2*W->irfft2), in place -------
__global__ __launch_bounds__(256) void k_pconv(u16* __restrict__ mid,
                                               const float* __restrict__ fw) {
  __shared__ float kk[64];
  const int bx = blockIdx.x;                // ((b*C2 + o) << 2) | q
  const int q  = bx & 3;
  const int bo = bx >> 2;
  const int o  = bo % C2;
  const int b  = bo / C2;
  if (threadIdx.x < 64) {                   // k = irfft2(fft_w[o]) via cos table
    const int a = threadIdx.x >> 3, bb = threadIdx.x & 7;
    float acc = 0.f;
    for (int u = 0; u < 8; ++u)
      for (int v = 0; v < 8; ++v) {
        const float wv = (v <= 4) ? fw[o*40 + u*5 + v]
                                  : fw[o*40 + ((8-u)&7)*5 + (8-v)];
        acc += wv * COSTAB[(u*a + v*bb) & 7];
      }
    kk[threadIdx.x] = acc * (1.f/64.f);
  }
  __syncthreads();
  const int pid = q*256 + threadIdx.x;      // patch id 0..1023
  const int py = pid >> 5, px = pid & 31;
  u16* base = mid + ((size_t)(b*C2 + o)) * HW + (size_t)(py*8) * WID + px*8;
  float xx[64];
  #pragma unroll
  for (int i = 0; i < 8; ++i) {
    const uint4 r = *(const uint4*)(base + i*WID);
    xx[i*8+0] = bf2f((u16)(r.x & 0xffffu)); xx[i*8+1] = bf2f((u16)(r.x >> 16));
    xx[i*8+2] = bf2f((u16)(r.y & 0xffffu)); xx[i*8+3] = bf2f((u16)(r.y >> 16));
    xx[i*8+4] = bf2f((u16)(r.z & 0xffffu)); xx[i*8+5] = bf2f((u16)(r.z >> 16));
    xx[i*8+6] = bf2f((u16)(r.w & 0xffffu)); xx[i*8+7] = bf2f((u16)(r.w >> 16));
  }
  float yy[64];
  #pragma unroll
  for (int t = 0; t < 64; ++t) yy[t] = 0.f;
  #pragma unroll
  for (int m = 0; m < 64; ++m) {
    const float kv = kk[m];
    const int mi = m >> 3, mj = m & 7;
    #pragma unroll
    for (int t = 0; t < 64; ++t) {
      yy[t] += kv * xx[((((t>>3) - mi) & 7) << 3) | (((t&7) - mj) & 7)];
    }
  }
  #pragma unroll
  for (int i = 0; i < 8; ++i) {
    uint4 s;
    s.x = (u32)f2bf(yy[i*8+0]) | ((u32)f2bf(yy[i*8+1]) << 16);
    s.y = (u32)f2bf(yy[i*8+2]) | ((u32)f2bf(yy[i*8+3]) << 16);
    s.z = (u32)f2bf(yy[i*8+4]) | ((u32)f2bf(yy[i*8+5]) << 16);
    s.w = (u32)f2bf(yy[i*8+6]) | ((u32)f2bf(yy[i*8+7]) << 16);
    *(uint4*)(base + i*WID) = s;
  }
}

// ------- K3: depthwise 3x3 + exact GELU gate + project_out (170 -> 64) -------
__global__ __launch_bounds__(256) void k_out(const u16* __restrict__ mid,
                                             const float* __restrict__ w_dw,
                                             const float* __restrict__ w_out,
                                             float* __restrict__ out) {
  __shared__ u16 sh[170 * 100];             // chunk of 170 channels, 10x10 halo tile
  __shared__ u16 gl[HID * 64];              // gate output, bf16
  const int bx = blockIdx.x;                // b*1024 + ty*32 + tx
  const int b = bx >> 10;
  const int t = bx & 1023;
  const int ty = t >> 5, tx = t & 31;
  const int h0 = ty * 8, w0 = tx * 8;

  for (int ck = 0; ck < 2; ++ck) {
    __syncthreads();                        // protect sh from previous chunk readers
    for (int idx = threadIdx.x; idx < 170*100; idx += 256) {
      const int s = idx / 100;
      const int r = idx - s * 100;
      const int ch = (s < 85) ? (ck*85 + s) : (170 + ck*85 + (s - 85));
      const int ri = r / 10;
      const int hh = h0 + ri - 1, ww = w0 + (r - ri*10) - 1;
      u16 v = 0;
      if (hh >= 0 && hh < HGT && ww >= 0 && ww < WID)
        v = mid[((size_t)(b*C2 + ch)) * HW + (size_t)hh * WID + ww];
      sh[idx] = v;
    }
    __syncthreads();
    for (int idx = threadIdx.x; idx < 85*64; idx += 256) {
      const int oo = idx >> 6;              // 0..84 within chunk
      const int p = idx & 63;
      const int i = p >> 3, j = p & 7;
      const int o = ck*85 + oo;
      const u16* s1 = sh + oo*100 + i*10 + j;
      const u16* s2 = sh + (85+oo)*100 + i*10 + j;
      const float* wd1 = w_dw + o*9;
      const float* wd2 = w_dw + (o+HID)*9;
      float a1 = 0.f, a2 = 0.f;
      #pragma unroll
      for (int ki = 0; ki < 3; ++ki)
        #pragma unroll
        for (int kj = 0; kj < 3; ++kj) {
          a1 += wd1[ki*3+kj] * bf2f(s1[ki*10+kj]);
          a2 += wd2[ki*3+kj] * bf2f(s2[ki*10+kj]);
        }
      const float g = 0.5f * a1 * (1.f + erff(a1 * 0.70710678118654752f)) * a2;
      gl[o*64 + p] = f2bf(g);
    }
  }
  __syncthreads();
  const int p  = threadIdx.x & 63;          // pixel in 8x8 tile
  const int og = threadIdx.x >> 6;          // out-channel group (16 each)
  float acc[16];
  #pragma unroll
  for (int d = 0; d < 16; ++d) acc[d] = 0.f;
  for (int o = 0; o < HID; ++o) {
    const float gv = bf2f(gl[o*64 + p]);
    #pragma unroll
    for (int d = 0; d < 16; ++d)
      acc[d] += w_out[(og*16 + d)*HID + o] * gv;
  }
  const int i = p >> 3, j = p & 7;
  float* ob = out + ((size_t)b*64) * HW + (size_t)(h0 + i) * WID + (w0 + j);
  #pragma unroll
  for (int d = 0; d < 16; ++d)
    ob[((size_t)(og*16 + d)) * HW] = acc[d];
}

extern "C" void kernel_launch(void* const* d_in, const int* in_sizes, int n_in,
                              void* d_out, int out_size, void* d_ws, size_t ws_size,
                              hipStream_t stream) {
  const float* x     = (const float*)d_in[0];
  const float* w_in  = (const float*)d_in[1];
  const float* w_dw  = (const float*)d_in[2];
  const float* fw    = (const float*)d_in[3];
  const float* w_out = (const float*)d_in[4];
  float* out = (float*)d_out;
  u16* mid = (u16*)d_ws;                    // [4,340,256,256] bf16 = 178 MB

  k_projin<<<NB*HGT, 256, 0, stream>>>(x, w_in, mid);
  k_pconv<<<NB*C2*4, 256, 0, stream>>>(mid, fw);
  k_out<<<NB*1024, 256, 0, stream>>>(mid, w_dw, w_out, out);
}

// Round 2
// 1101.009 us; speedup vs baseline: 1.7228x; 1.7228x over previous
//
#include <hip/hip_runtime.h>
#include <hip/hip_bf16.h>

#define C2 340
#define HID 170
#define NB 4
#define HGT 256
#define WID 256
#define HW (HGT*WID)
#define BAND 128

typedef unsigned short u16;
typedef unsigned int u32;

__device__ __forceinline__ float bf2f(u16 u) {
  union { u32 i; float f; } v; v.i = ((u32)u) << 16; return v.f;
}
__device__ __forceinline__ u16 f2bf(float f) {
  union { float f; u32 i; } v; v.f = f;
  u32 x = v.i;
  return (u16)((x + 0x7fffu + ((x >> 16) & 1u)) >> 16);
}

__device__ const float COSTAB[8] = {1.f, 0.70710678118654752f, 0.f, -0.70710678118654752f,
                                    -1.f, -0.70710678118654752f, 0.f, 0.70710678118654752f};

// ---------------- K1: project_in (64 -> 340), register-resident ----------------
__global__ __launch_bounds__(256) void k_projin(const float* __restrict__ x,
                                                const float* __restrict__ w_in,
                                                u16* __restrict__ mid) {
  const int b = blockIdx.x >> 8;                      // 256 blocks per batch
  const int pix = ((blockIdx.x & 255) << 8) + threadIdx.x;   // 0..65535
  const float* xp = x + (size_t)b * 64 * HW + pix;
  float xv[64];
  #pragma unroll
  for (int c = 0; c < 64; ++c) xv[c] = xp[(size_t)c * HW];
  u16* mp = mid + (size_t)b * C2 * HW + pix;
  for (int ob = 0; ob < 85; ++ob) {                   // 85 * 4 = 340 out channels
    const float* wr = w_in + ob * 4 * 64;             // uniform -> s_load
    float a0 = 0.f, a1 = 0.f, a2 = 0.f, a3 = 0.f;
    #pragma unroll
    for (int c = 0; c < 64; ++c) {
      const float xc = xv[c];
      a0 += wr[c] * xc;
      a1 += wr[64 + c] * xc;
      a2 += wr[128 + c] * xc;
      a3 += wr[192 + c] * xc;
    }
    mp[(size_t)(ob*4 + 0) * HW] = f2bf(a0);
    mp[(size_t)(ob*4 + 1) * HW] = f2bf(a1);
    mp[(size_t)(ob*4 + 2) * HW] = f2bf(a2);
    mp[(size_t)(ob*4 + 3) * HW] = f2bf(a3);
  }
}

// ------- K2: per-channel 8x8 circular conv (== rfft2*W->irfft2), in place -------
__global__ __launch_bounds__(256) void k_pconv(u16* __restrict__ mid,
                                               const float* __restrict__ fw) {
  __shared__ float kk[64];
  const int bx = blockIdx.x;                // ((b*C2 + o) << 2) | q
  const int q  = bx & 3;
  const int bo = bx >> 2;
  const int o  = bo % C2;
  const int b  = bo / C2;
  if (threadIdx.x < 64) {                   // k = irfft2(fft_w[o]) via cos table
    const int a = threadIdx.x >> 3, bb = threadIdx.x & 7;
    float acc = 0.f;
    for (int u = 0; u < 8; ++u)
      for (int v = 0; v < 8; ++v) {
        const float wv = (v <= 4) ? fw[o*40 + u*5 + v]
                                  : fw[o*40 + ((8-u)&7)*5 + (8-v)];
        acc += wv * COSTAB[(u*a + v*bb) & 7];
      }
    kk[threadIdx.x] = acc * (1.f/64.f);
  }
  __syncthreads();
  const int pid = q*256 + threadIdx.x;      // patch id 0..1023
  const int py = pid >> 5, px = pid & 31;
  u16* base = mid + ((size_t)(b*C2 + o)) * HW + (size_t)(py*8) * WID + px*8;
  float xx[64];
  #pragma unroll
  for (int i = 0; i < 8; ++i) {
    const uint4 r = *(const uint4*)(base + i*WID);
    xx[i*8+0] = bf2f((u16)(r.x & 0xffffu)); xx[i*8+1] = bf2f((u16)(r.x >> 16));
    xx[i*8+2] = bf2f((u16)(r.y & 0xffffu)); xx[i*8+3] = bf2f((u16)(r.y >> 16));
    xx[i*8+4] = bf2f((u16)(r.z & 0xffffu)); xx[i*8+5] = bf2f((u16)(r.z >> 16));
    xx[i*8+6] = bf2f((u16)(r.w & 0xffffu)); xx[i*8+7] = bf2f((u16)(r.w >> 16));
  }
  float yy[64];
  #pragma unroll
  for (int t = 0; t < 64; ++t) yy[t] = 0.f;
  #pragma unroll
  for (int m = 0; m < 64; ++m) {
    const float kv = kk[m];
    const int mi = m >> 3, mj = m & 7;
    #pragma unroll
    for (int t = 0; t < 64; ++t) {
      yy[t] += kv * xx[((((t>>3) - mi) & 7) << 3) | (((t&7) - mj) & 7)];
    }
  }
  #pragma unroll
  for (int i = 0; i < 8; ++i) {
    uint4 s;
    s.x = (u32)f2bf(yy[i*8+0]) | ((u32)f2bf(yy[i*8+1]) << 16);
    s.y = (u32)f2bf(yy[i*8+2]) | ((u32)f2bf(yy[i*8+3]) << 16);
    s.z = (u32)f2bf(yy[i*8+4]) | ((u32)f2bf(yy[i*8+5]) << 16);
    s.w = (u32)f2bf(yy[i*8+6]) | ((u32)f2bf(yy[i*8+7]) << 16);
    *(uint4*)(base + i*WID) = s;
  }
}

// ------- K3a: depthwise 3x3 + exact GELU gate, band-wise, coalesced -------
__global__ __launch_bounds__(256) void k_gate(const u16* __restrict__ mid,
                                              const float* __restrict__ w_dw,
                                              u16* __restrict__ gbuf, int hb) {
  __shared__ __align__(16) u16 sh[2][18][272];  // [8 pad][256 data][8 pad], 19.6 KB
  const int s  = blockIdx.x & 7;            // 16-row slice within 128-row super-band
  const int bc = blockIdx.x >> 3;
  const int c  = bc % HID, b = bc / HID;
  const int h0 = hb + s * 16;

  u32* shw = (u32*)sh;
  for (int i = threadIdx.x; i < 2*18*136; i += 256) shw[i] = 0;
  __syncthreads();
  for (int i = threadIdx.x; i < 2*18*32; i += 256) {  // uint4 = 8 u16 per task
    const int k = i & 31;
    const int r = (i >> 5) % 18;
    const int ch2 = i / (18*32);
    const int h = h0 + r - 1;
    if (h >= 0 && h < HGT) {
      const u16* src = mid + ((size_t)(b*C2 + c + ch2*HID)) * HW + (size_t)h * WID + k*8;
      *(uint4*)&sh[ch2][r][8 + k*8] = *(const uint4*)src;
    }
  }
  __syncthreads();

  const int cc = threadIdx.x;               // column 0..255
  const float* wd1 = w_dw + c * 9;          // uniform -> s_load
  const float* wd2 = w_dw + (c + HID) * 9;
  u16* gp = gbuf + (((size_t)(b*HID + c)) * BAND + (h0 - hb)) * WID + cc;

  float A[3][3], B2[3][3];
  #pragma unroll
  for (int ri = 0; ri < 2; ++ri)
    #pragma unroll
    for (int j = 0; j < 3; ++j) {
      A[ri][j]  = bf2f(sh[0][ri][7 + cc + j]);
      B2[ri][j] = bf2f(sh[1][ri][7 + cc + j]);
    }
  #pragma unroll 4
  for (int r = 0; r < 16; ++r) {
    #pragma unroll
    for (int j = 0; j < 3; ++j) {
      A[2][j]  = bf2f(sh[0][r+2][7 + cc + j]);
      B2[2][j] = bf2f(sh[1][r+2][7 + cc + j]);
    }
    float a1 = 0.f, a2 = 0.f;
    #pragma unroll
    for (int ri = 0; ri < 3; ++ri)
      #pragma unroll
      for (int j = 0; j < 3; ++j) {
        a1 += wd1[ri*3 + j] * A[ri][j];
        a2 += wd2[ri*3 + j] * B2[ri][j];
      }
    const float g = 0.5f * a1 * (1.f + erff(a1 * 0.70710678118654752f)) * a2;
    gp[(size_t)r * WID] = f2bf(g);
    #pragma unroll
    for (int j = 0; j < 3; ++j) {
      A[0][j] = A[1][j];  A[1][j] = A[2][j];
      B2[0][j] = B2[1][j]; B2[1][j] = B2[2][j];
    }
  }
}

// ------- tiny: transpose w_out [64][170] -> wT [170][64] -------
__global__ void k_wt(const float* __restrict__ w_out, float* __restrict__ wT) {
  const int i = blockIdx.x * 256 + threadIdx.x;
  if (i < HID * 64) {
    const int c = i >> 6, d = i & 63;
    wT[c * 64 + d] = w_out[d * HID + c];
  }
}

// ------- K3b: project_out (170 -> 64), thread-per-pixel, acc[64] -------
__global__ __launch_bounds__(256) void k_projout(const u16* __restrict__ gbuf,
                                                 const float* __restrict__ wT,
                                                 float* __restrict__ out, int hb) {
  const int t = blockIdx.x * 256 + threadIdx.x;   // 0..131071 (4 b x 128 rows x 256)
  const int b = t >> 15;
  const int p = t & 32767;                        // row*256+col within super-band
  const u16* g = gbuf + (size_t)b * HID * BAND * WID + p;
  float acc[64];
  #pragma unroll
  for (int d = 0; d < 64; ++d) acc[d] = 0.f;
  for (int c = 0; c < HID; ++c) {
    const float gv = bf2f(g[(size_t)c * BAND * WID]);
    const float* wr = wT + c * 64;                // uniform -> s_load
    #pragma unroll
    for (int d = 0; d < 64; ++d) acc[d] += wr[d] * gv;
  }
  float* op = out + (size_t)b * 64 * HW + (size_t)hb * WID + p;
  #pragma unroll
  for (int d = 0; d < 64; ++d) op[(size_t)d * HW] = acc[d];
}

extern "C" void kernel_launch(void* const* d_in, const int* in_sizes, int n_in,
                              void* d_out, int out_size, void* d_ws, size_t ws_size,
                              hipStream_t stream) {
  const float* x     = (const float*)d_in[0];
  const float* w_in  = (const float*)d_in[1];
  const float* w_dw  = (const float*)d_in[2];
  const float* fw    = (const float*)d_in[3];
  const float* w_out = (const float*)d_in[4];
  float* out = (float*)d_out;

  u16* mid  = (u16*)d_ws;                                    // 178,257,920 B
  u16* gbuf = (u16*)((char*)d_ws + (size_t)178257920);       // 44,564,480 B
  float* wT = (float*)((char*)d_ws + (size_t)178257920 + 44564480);  // 43,520 B

  k_wt<<<(HID*64 + 255)/256, 256, 0, stream>>>(w_out, wT);
  k_projin<<<NB*256, 256, 0, stream>>>(x, w_in, mid);
  k_pconv<<<NB*C2*4, 256, 0, stream>>>(mid, fw);
  for (int sb = 0; sb < 2; ++sb) {
    const int hb = sb * BAND;
    k_gate<<<NB*HID*8, 256, 0, stream>>>(mid, w_dw, gbuf, hb);
    k_projout<<<(NB*BAND*WID)/256, 256, 0, stream>>>(gbuf, wT, out, hb);
  }
}

// Round 3
// 483.188 us; speedup vs baseline: 3.9257x; 2.2786x over previous
//
#include <hip/hip_runtime.h>
#include <hip/hip_bf16.h>

#define C2 340
#define HID 170
#define NB 4
#define HGT 256
#define WID 256
#define HW (HGT*WID)
#define BAND 128

typedef unsigned short u16;
typedef unsigned int u32;
typedef float f32x4 __attribute__((ext_vector_type(4)));
typedef short s16x8 __attribute__((ext_vector_type(8)));

__device__ __forceinline__ float bf2f(u16 u) {
  union { u32 i; float f; } v; v.i = ((u32)u) << 16; return v.f;
}
__device__ __forceinline__ u16 f2bf(float f) {
  union { float f; u32 i; } v; v.f = f;
  u32 x = v.i;
  return (u16)((x + 0x7fffu + ((x >> 16) & 1u)) >> 16);
}

__device__ const float COSTAB[8] = {1.f, 0.70710678118654752f, 0.f, -0.70710678118654752f,
                                    -1.f, -0.70710678118654752f, 0.f, 0.70710678118654752f};

// ---------------- K1: project_in (64 -> 340), register-resident ----------------
__global__ __launch_bounds__(256) void k_projin(const float* __restrict__ x,
                                                const float* __restrict__ w_in,
                                                u16* __restrict__ mid) {
  const int b = blockIdx.x >> 8;                      // 256 blocks per batch
  const int pix = ((blockIdx.x & 255) << 8) + threadIdx.x;   // 0..65535
  const float* xp = x + (size_t)b * 64 * HW + pix;
  float xv[64];
  #pragma unroll
  for (int c = 0; c < 64; ++c) xv[c] = xp[(size_t)c * HW];
  u16* mp = mid + (size_t)b * C2 * HW + pix;
  for (int ob = 0; ob < 85; ++ob) {                   // 85 * 4 = 340 out channels
    const float* wr = w_in + ob * 4 * 64;             // uniform -> s_load
    float a0 = 0.f, a1 = 0.f, a2 = 0.f, a3 = 0.f;
    #pragma unroll
    for (int c = 0; c < 64; ++c) {
      const float xc = xv[c];
      a0 += wr[c] * xc;
      a1 += wr[64 + c] * xc;
      a2 += wr[128 + c] * xc;
      a3 += wr[192 + c] * xc;
    }
    mp[(size_t)(ob*4 + 0) * HW] = f2bf(a0);
    mp[(size_t)(ob*4 + 1) * HW] = f2bf(a1);
    mp[(size_t)(ob*4 + 2) * HW] = f2bf(a2);
    mp[(size_t)(ob*4 + 3) * HW] = f2bf(a3);
  }
}

// ------- prepass: build per-channel conv matrix in MFMA B-fragment order -------
// Mfrag[c][nblk*2+s][lane][r] (bf16), B[k][n] = kern[(i-a)&7][(j-b)&7]
//   k = s*32 + (lane>>4)*8 + r = a*8+b ;  n = nblk*16 + (lane&15) = i*8+j
__global__ __launch_bounds__(256) void k_mfrag(const float* __restrict__ fw,
                                               u16* __restrict__ mf) {
  __shared__ float kern[64];
  const int c = blockIdx.x;
  if (threadIdx.x < 64) {
    const int a = threadIdx.x >> 3, bb = threadIdx.x & 7;
    float acc = 0.f;
    for (int u = 0; u < 8; ++u)
      for (int v = 0; v < 8; ++v) {
        const float wv = (v <= 4) ? fw[c*40 + u*5 + v]
                                  : fw[c*40 + ((8-u)&7)*5 + (8-v)];
        acc += wv * COSTAB[(u*a + v*bb) & 7];
      }
    kern[threadIdx.x] = acc * (1.f/64.f);
  }
  __syncthreads();
  #pragma unroll
  for (int q = 0; q < 16; ++q) {
    const int e = q * 256 + threadIdx.x;      // 0..4095
    const int r = e & 7;
    const int l = (e >> 3) & 63;
    const int sb = e >> 9;                    // nblk*2 + s
    const int s = sb & 1, nblk = sb >> 1;
    const int k = s*32 + ((l >> 4) << 3) + r;
    const int a = k >> 3, bcol = k & 7;
    const int n = nblk*16 + (l & 15);
    const int i = n >> 3, j = n & 7;
    mf[(size_t)c * 4096 + e] = f2bf(kern[(((i - a) & 7) << 3) + ((j - bcol) & 7)]);
  }
}

// ------- K2: per-channel 8x8 circular conv as MFMA GEMM, in place -------
// per (b,c):  Y[1024 patches x 64 pix] = X[1024 x 64] * M_c[64 x 64]
__global__ __launch_bounds__(256) void k_pconv2(u16* __restrict__ mid,
                                                const u16* __restrict__ mf) {
  const int gid = blockIdx.x;               // 2*(b*C2+c) + half
  const int half = gid & 1;
  const int bc = gid >> 1;
  const int c = bc % C2;
  const int lane = threadIdx.x & 63;
  const int w = threadIdx.x >> 6;
  u16* chan = mid + (size_t)bc * HW;

  s16x8 Bf[4][2];
  const u16* mfc = mf + (size_t)c * 4096;
  #pragma unroll
  for (int nb = 0; nb < 4; ++nb)
    #pragma unroll
    for (int s = 0; s < 2; ++s)
      Bf[nb][s] = *(const s16x8*)(mfc + ((nb*2 + s)*64 + lane)*8);

  const int lm = lane & 15, lh = lane >> 4;
  for (int it = 0; it < 8; ++it) {
    const int pg = half*512 + (it*4 + w)*16;  // 16-patch group base
    const int py = pg >> 5, px0 = pg & 31;
    // A: lane -> patch pg+lm, row lh (+4 for step 1); 16B contiguous per 16 lanes
    const u16* aptr = chan + (size_t)(py*8 + lh)*WID + (px0 + lm)*8;
    const s16x8 A0 = *(const s16x8*)(aptr);
    const s16x8 A1 = *(const s16x8*)(aptr + 4*WID);
    f32x4 ac0 = {0.f,0.f,0.f,0.f}, ac1 = {0.f,0.f,0.f,0.f};
    f32x4 ac2 = {0.f,0.f,0.f,0.f}, ac3 = {0.f,0.f,0.f,0.f};
    ac0 = __builtin_amdgcn_mfma_f32_16x16x32_bf16(A0, Bf[0][0], ac0, 0,0,0);
    ac0 = __builtin_amdgcn_mfma_f32_16x16x32_bf16(A1, Bf[0][1], ac0, 0,0,0);
    ac1 = __builtin_amdgcn_mfma_f32_16x16x32_bf16(A0, Bf[1][0], ac1, 0,0,0);
    ac1 = __builtin_amdgcn_mfma_f32_16x16x32_bf16(A1, Bf[1][1], ac1, 0,0,0);
    ac2 = __builtin_amdgcn_mfma_f32_16x16x32_bf16(A0, Bf[2][0], ac2, 0,0,0);
    ac2 = __builtin_amdgcn_mfma_f32_16x16x32_bf16(A1, Bf[2][1], ac2, 0,0,0);
    ac3 = __builtin_amdgcn_mfma_f32_16x16x32_bf16(A0, Bf[3][0], ac3, 0,0,0);
    ac3 = __builtin_amdgcn_mfma_f32_16x16x32_bf16(A1, Bf[3][1], ac3, 0,0,0);
    // D: lane holds patch pg + lh*4 + r, pixel n = nblk*16 + lm
    u16* optr = chan + (size_t)(py*8 + (lm >> 3))*WID + (px0 + lh*4)*8 + (lane & 7);
    #pragma unroll
    for (int r = 0; r < 4; ++r) {
      optr[r*8 +    0] = f2bf(ac0[r]);
      optr[r*8 +  512] = f2bf(ac1[r]);
      optr[r*8 + 1024] = f2bf(ac2[r]);
      optr[r*8 + 1536] = f2bf(ac3[r]);
    }
  }
}

// ------- K3a: depthwise 3x3 + exact GELU gate, band-wise, coalesced -------
__global__ __launch_bounds__(256) void k_gate(const u16* __restrict__ mid,
                                              const float* __restrict__ w_dw,
                                              u16* __restrict__ gbuf, int hb) {
  __shared__ __align__(16) u16 sh[2][18][272];  // [8 pad][256 data][8 pad], 19.6 KB
  const int s  = blockIdx.x & 7;            // 16-row slice within 128-row super-band
  const int bc = blockIdx.x >> 3;
  const int c  = bc % HID, b = bc / HID;
  const int h0 = hb + s * 16;

  u32* shw = (u32*)sh;
  for (int i = threadIdx.x; i < 2*18*136; i += 256) shw[i] = 0;
  __syncthreads();
  for (int i = threadIdx.x; i < 2*18*32; i += 256) {  // uint4 = 8 u16 per task
    const int k = i & 31;
    const int r = (i >> 5) % 18;
    const int ch2 = i / (18*32);
    const int h = h0 + r - 1;
    if (h >= 0 && h < HGT) {
      const u16* src = mid + ((size_t)(b*C2 + c + ch2*HID)) * HW + (size_t)h * WID + k*8;
      *(uint4*)&sh[ch2][r][8 + k*8] = *(const uint4*)src;
    }
  }
  __syncthreads();

  const int cc = threadIdx.x;               // column 0..255
  const float* wd1 = w_dw + c * 9;          // uniform -> s_load
  const float* wd2 = w_dw + (c + HID) * 9;
  u16* gp = gbuf + (((size_t)(b*HID + c)) * BAND + (h0 - hb)) * WID + cc;

  float A[3][3], B2[3][3];
  #pragma unroll
  for (int ri = 0; ri < 2; ++ri)
    #pragma unroll
    for (int j = 0; j < 3; ++j) {
      A[ri][j]  = bf2f(sh[0][ri][7 + cc + j]);
      B2[ri][j] = bf2f(sh[1][ri][7 + cc + j]);
    }
  #pragma unroll 4
  for (int r = 0; r < 16; ++r) {
    #pragma unroll
    for (int j = 0; j < 3; ++j) {
      A[2][j]  = bf2f(sh[0][r+2][7 + cc + j]);
      B2[2][j] = bf2f(sh[1][r+2][7 + cc + j]);
    }
    float a1 = 0.f, a2 = 0.f;
    #pragma unroll
    for (int ri = 0; ri < 3; ++ri)
      #pragma unroll
      for (int j = 0; j < 3; ++j) {
        a1 += wd1[ri*3 + j] * A[ri][j];
        a2 += wd2[ri*3 + j] * B2[ri][j];
      }
    const float g = 0.5f * a1 * (1.f + erff(a1 * 0.70710678118654752f)) * a2;
    gp[(size_t)r * WID] = f2bf(g);
    #pragma unroll
    for (int j = 0; j < 3; ++j) {
      A[0][j] = A[1][j];  A[1][j] = A[2][j];
      B2[0][j] = B2[1][j]; B2[1][j] = B2[2][j];
    }
  }
}

// ------- tiny: transpose w_out [64][170] -> wT [170][64] -------
__global__ void k_wt(const float* __restrict__ w_out, float* __restrict__ wT) {
  const int i = blockIdx.x * 256 + threadIdx.x;
  if (i < HID * 64) {
    const int c = i >> 6, d = i & 63;
    wT[c * 64 + d] = w_out[d * HID + c];
  }
}

// ------- K3b: project_out (170 -> 64), thread-per-pixel, acc[64] -------
__global__ __launch_bounds__(256) void k_projout(const u16* __restrict__ gbuf,
                                                 const float* __restrict__ wT,
                                                 float* __restrict__ out, int hb) {
  const int t = blockIdx.x * 256 + threadIdx.x;   // 0..131071 (4 b x 128 rows x 256)
  const int b = t >> 15;
  const int p = t & 32767;                        // row*256+col within super-band
  const u16* g = gbuf + (size_t)b * HID * BAND * WID + p;
  float acc[64];
  #pragma unroll
  for (int d = 0; d < 64; ++d) acc[d] = 0.f;
  for (int c = 0; c < HID; ++c) {
    const float gv = bf2f(g[(size_t)c * BAND * WID]);
    const float* wr = wT + c * 64;                // uniform -> s_load
    #pragma unroll
    for (int d = 0; d < 64; ++d) acc[d] += wr[d] * gv;
  }
  float* op = out + (size_t)b * 64 * HW + (size_t)hb * WID + p;
  #pragma unroll
  for (int d = 0; d < 64; ++d) op[(size_t)d * HW] = acc[d];
}

extern "C" void kernel_launch(void* const* d_in, const int* in_sizes, int n_in,
                              void* d_out, int out_size, void* d_ws, size_t ws_size,
                              hipStream_t stream) {
  const float* x     = (const float*)d_in[0];
  const float* w_in  = (const float*)d_in[1];
  const float* w_dw  = (const float*)d_in[2];
  const float* fw    = (const float*)d_in[3];
  const float* w_out = (const float*)d_in[4];
  float* out = (float*)d_out;

  u16* mid  = (u16*)d_ws;                                    // 178,257,920 B
  u16* gbuf = (u16*)((char*)d_ws + (size_t)178257920);       // 44,564,480 B
  float* wT = (float*)((char*)d_ws + (size_t)178257920 + 44564480);  // 43,520 B
  u16* mfrag = (u16*)((char*)d_ws + (size_t)178257920 + 44564480 + 43520); // 2,785,280 B

  k_wt<<<(HID*64 + 255)/256, 256, 0, stream>>>(w_out, wT);
  k_mfrag<<<C2, 256, 0, stream>>>(fw, mfrag);
  k_projin<<<NB*256, 256, 0, stream>>>(x, w_in, mid);
  k_pconv2<<<NB*C2*2, 256, 0, stream>>>(mid, mfrag);
  for (int sb = 0; sb < 2; ++sb) {
    const int hb = sb * BAND;
    k_gate<<<NB*HID*8, 256, 0, stream>>>(mid, w_dw, gbuf, hb);
    k_projout<<<(NB*BAND*WID)/256, 256, 0, stream>>>(gbuf, wT, out, hb);
  }
}

// Round 4
// 376.458 us; speedup vs baseline: 5.0387x; 1.2835x over previous
//
#include <hip/hip_runtime.h>
#include <hip/hip_bf16.h>

#define C2 340
#define HID 170
#define NB 4
#define HGT 256
#define WID 256
#define HW (HGT*WID)
#define BAND 128

typedef unsigned short u16;
typedef unsigned int u32;
typedef float f32x4 __attribute__((ext_vector_type(4)));
typedef short s16x8 __attribute__((ext_vector_type(8)));

__device__ __forceinline__ float bf2f(u16 u) {
  union { u32 i; float f; } v; v.i = ((u32)u) << 16; return v.f;
}
__device__ __forceinline__ u16 f2bf(float f) {
  union { float f; u32 i; } v; v.f = f;
  u32 x = v.i;
  return (u16)((x + 0x7fffu + ((x >> 16) & 1u)) >> 16);
}

__device__ const float COSTAB[8] = {1.f, 0.70710678118654752f, 0.f, -0.70710678118654752f,
                                    -1.f, -0.70710678118654752f, 0.f, 0.70710678118654752f};

// ------- prepass: transpose x [b][64][HW] f32 -> xt [b][pix][64] bf16 -------
__global__ __launch_bounds__(256) void k_xt(const float* __restrict__ x,
                                            u16* __restrict__ xt) {
  const int b = blockIdx.x >> 8;
  const int pix = ((blockIdx.x & 255) << 8) + threadIdx.x;
  const float* xp = x + (size_t)b * 64 * HW + pix;
  float v[64];
  #pragma unroll
  for (int c = 0; c < 64; ++c) v[c] = xp[(size_t)c * HW];
  u32 pk[32];
  #pragma unroll
  for (int i = 0; i < 32; ++i)
    pk[i] = (u32)f2bf(v[2*i]) | ((u32)f2bf(v[2*i+1]) << 16);
  uint4* op = (uint4*)(xt + ((size_t)b * 65536 + pix) * 64);
  #pragma unroll
  for (int i = 0; i < 8; ++i)
    op[i] = make_uint4(pk[4*i], pk[4*i+1], pk[4*i+2], pk[4*i+3]);
}

// ------- prepass: W [340][64] f32 -> bf16 A-fragments, padded to 352 rows -------
// Af[t][s][lane][r] = W[m=t*16+(lane&15)][k=s*32+(lane>>4)*8+r], 0 if m>=340
__global__ __launch_bounds__(256) void k_wfrag(const float* __restrict__ w_in,
                                               u16* __restrict__ wf) {
  for (int e = threadIdx.x; e < 22*2*64*8; e += 256) {
    const int r = e & 7;
    const int l = (e >> 3) & 63;
    const int ts = e >> 9;
    const int s = ts & 1, t = ts >> 1;
    const int m = t*16 + (l & 15);
    const int k = s*32 + ((l >> 4) << 3) + r;
    wf[e] = (m < C2) ? f2bf(w_in[m*64 + k]) : (u16)0;
  }
}

// ---------------- K1: project_in (64 -> 340) via MFMA ----------------
__global__ __launch_bounds__(256) void k_projin2(const u16* __restrict__ xt,
                                                 const u16* __restrict__ wf,
                                                 u16* __restrict__ mid) {
  __shared__ __align__(16) u16 aw[22*2*64*8];     // 45056 B
  for (int i = threadIdx.x; i < 22*2*64; i += 256)
    ((uint4*)aw)[i] = ((const uint4*)wf)[i];
  __syncthreads();
  const int b = blockIdx.x >> 8;
  const int pix0 = ((blockIdx.x & 255) << 8) | ((threadIdx.x >> 6) << 6);
  const int lane = threadIdx.x & 63;
  const int lm = lane & 15, lh = lane >> 4;

  s16x8 Bf[4][2];                                  // 4 pixel groups x 2 ksteps
  const u16* xp = xt + ((size_t)b * 65536 + pix0) * 64;
  #pragma unroll
  for (int g = 0; g < 4; ++g) {
    const u16* p = xp + (g*16 + lm)*64 + lh*8;
    Bf[g][0] = *(const s16x8*)(p);
    Bf[g][1] = *(const s16x8*)(p + 32);
  }
  u16* mp = mid + (size_t)b * C2 * HW + pix0;
  for (int t = 0; t < 22; ++t) {
    const s16x8 A0 = *(const s16x8*)(aw + ((t*2 + 0)*64 + lane)*8);
    const s16x8 A1 = *(const s16x8*)(aw + ((t*2 + 1)*64 + lane)*8);
    f32x4 ac[4];
    #pragma unroll
    for (int g = 0; g < 4; ++g) {
      ac[g] = (f32x4){0.f,0.f,0.f,0.f};
      ac[g] = __builtin_amdgcn_mfma_f32_16x16x32_bf16(A0, Bf[g][0], ac[g], 0,0,0);
      ac[g] = __builtin_amdgcn_mfma_f32_16x16x32_bf16(A1, Bf[g][1], ac[g], 0,0,0);
    }
    const int ch0 = t*16 + lh*4;                   // D row = channel
    #pragma unroll
    for (int r = 0; r < 4; ++r) {
      const int ch = ch0 + r;
      if (ch < C2) {
        #pragma unroll
        for (int g = 0; g < 4; ++g)
          mp[(size_t)ch * HW + g*16 + lm] = f2bf(ac[g][r]);
      }
    }
  }
}

// ------- prepass: build per-channel conv matrix in MFMA B-fragment order -------
__global__ __launch_bounds__(256) void k_mfrag(const float* __restrict__ fw,
                                               u16* __restrict__ mf) {
  __shared__ float kern[64];
  const int c = blockIdx.x;
  if (threadIdx.x < 64) {
    const int a = threadIdx.x >> 3, bb = threadIdx.x & 7;
    float acc = 0.f;
    for (int u = 0; u < 8; ++u)
      for (int v = 0; v < 8; ++v) {
        const float wv = (v <= 4) ? fw[c*40 + u*5 + v]
                                  : fw[c*40 + ((8-u)&7)*5 + (8-v)];
        acc += wv * COSTAB[(u*a + v*bb) & 7];
      }
    kern[threadIdx.x] = acc * (1.f/64.f);
  }
  __syncthreads();
  #pragma unroll
  for (int q = 0; q < 16; ++q) {
    const int e = q * 256 + threadIdx.x;
    const int r = e & 7;
    const int l = (e >> 3) & 63;
    const int sb = e >> 9;
    const int s = sb & 1, nblk = sb >> 1;
    const int k = s*32 + ((l >> 4) << 3) + r;
    const int a = k >> 3, bcol = k & 7;
    const int n = nblk*16 + (l & 15);
    const int i = n >> 3, j = n & 7;
    mf[(size_t)c * 4096 + e] = f2bf(kern[(((i - a) & 7) << 3) + ((j - bcol) & 7)]);
  }
}

// ------- K2: per-channel 8x8 circular conv as MFMA GEMM, in place -------
__global__ __launch_bounds__(256) void k_pconv2(u16* __restrict__ mid,
                                                const u16* __restrict__ mf) {
  const int gid = blockIdx.x;
  const int half = gid & 1;
  const int bc = gid >> 1;
  const int c = bc % C2;
  const int lane = threadIdx.x & 63;
  const int w = threadIdx.x >> 6;
  u16* chan = mid + (size_t)bc * HW;

  s16x8 Bf[4][2];
  const u16* mfc = mf + (size_t)c * 4096;
  #pragma unroll
  for (int nb = 0; nb < 4; ++nb)
    #pragma unroll
    for (int s = 0; s < 2; ++s)
      Bf[nb][s] = *(const s16x8*)(mfc + ((nb*2 + s)*64 + lane)*8);

  const int lm = lane & 15, lh = lane >> 4;
  for (int it = 0; it < 8; ++it) {
    const int pg = half*512 + (it*4 + w)*16;
    const int py = pg >> 5, px0 = pg & 31;
    const u16* aptr = chan + (size_t)(py*8 + lh)*WID + (px0 + lm)*8;
    const s16x8 A0 = *(const s16x8*)(aptr);
    const s16x8 A1 = *(const s16x8*)(aptr + 4*WID);
    f32x4 ac0 = {0.f,0.f,0.f,0.f}, ac1 = {0.f,0.f,0.f,0.f};
    f32x4 ac2 = {0.f,0.f,0.f,0.f}, ac3 = {0.f,0.f,0.f,0.f};
    ac0 = __builtin_amdgcn_mfma_f32_16x16x32_bf16(A0, Bf[0][0], ac0, 0,0,0);
    ac0 = __builtin_amdgcn_mfma_f32_16x16x32_bf16(A1, Bf[0][1], ac0, 0,0,0);
    ac1 = __builtin_amdgcn_mfma_f32_16x16x32_bf16(A0, Bf[1][0], ac1, 0,0,0);
    ac1 = __builtin_amdgcn_mfma_f32_16x16x32_bf16(A1, Bf[1][1], ac1, 0,0,0);
    ac2 = __builtin_amdgcn_mfma_f32_16x16x32_bf16(A0, Bf[2][0], ac2, 0,0,0);
    ac2 = __builtin_amdgcn_mfma_f32_16x16x32_bf16(A1, Bf[2][1], ac2, 0,0,0);
    ac3 = __builtin_amdgcn_mfma_f32_16x16x32_bf16(A0, Bf[3][0], ac3, 0,0,0);
    ac3 = __builtin_amdgcn_mfma_f32_16x16x32_bf16(A1, Bf[3][1], ac3, 0,0,0);
    u16* optr = chan + (size_t)(py*8 + (lm >> 3))*WID + (px0 + lh*4)*8 + (lane & 7);
    #pragma unroll
    for (int r = 0; r < 4; ++r) {
      optr[r*8 +    0] = f2bf(ac0[r]);
      optr[r*8 +  512] = f2bf(ac1[r]);
      optr[r*8 + 1024] = f2bf(ac2[r]);
      optr[r*8 + 1536] = f2bf(ac3[r]);
    }
  }
}

// ------- K3a: depthwise 3x3 + exact GELU gate, band-wise, coalesced -------
__global__ __launch_bounds__(256) void k_gate(const u16* __restrict__ mid,
                                              const float* __restrict__ w_dw,
                                              u16* __restrict__ gbuf, int hb) {
  __shared__ __align__(16) u16 sh[2][18][272];
  const int s  = blockIdx.x & 7;
  const int bc = blockIdx.x >> 3;
  const int c  = bc % HID, b = bc / HID;
  const int h0 = hb + s * 16;

  u32* shw = (u32*)sh;
  for (int i = threadIdx.x; i < 2*18*136; i += 256) shw[i] = 0;
  __syncthreads();
  for (int i = threadIdx.x; i < 2*18*32; i += 256) {
    const int k = i & 31;
    const int r = (i >> 5) % 18;
    const int ch2 = i / (18*32);
    const int h = h0 + r - 1;
    if (h >= 0 && h < HGT) {
      const u16* src = mid + ((size_t)(b*C2 + c + ch2*HID)) * HW + (size_t)h * WID + k*8;
      *(uint4*)&sh[ch2][r][8 + k*8] = *(const uint4*)src;
    }
  }
  __syncthreads();

  const int cc = threadIdx.x;
  const float* wd1 = w_dw + c * 9;
  const float* wd2 = w_dw + (c + HID) * 9;
  u16* gp = gbuf + (((size_t)(b*HID + c)) * BAND + (h0 - hb)) * WID + cc;

  float A[3][3], B2[3][3];
  #pragma unroll
  for (int ri = 0; ri < 2; ++ri)
    #pragma unroll
    for (int j = 0; j < 3; ++j) {
      A[ri][j]  = bf2f(sh[0][ri][7 + cc + j]);
      B2[ri][j] = bf2f(sh[1][ri][7 + cc + j]);
    }
  #pragma unroll 4
  for (int r = 0; r < 16; ++r) {
    #pragma unroll
    for (int j = 0; j < 3; ++j) {
      A[2][j]  = bf2f(sh[0][r+2][7 + cc + j]);
      B2[2][j] = bf2f(sh[1][r+2][7 + cc + j]);
    }
    float a1 = 0.f, a2 = 0.f;
    #pragma unroll
    for (int ri = 0; ri < 3; ++ri)
      #pragma unroll
      for (int j = 0; j < 3; ++j) {
        a1 += wd1[ri*3 + j] * A[ri][j];
        a2 += wd2[ri*3 + j] * B2[ri][j];
      }
    const float g = 0.5f * a1 * (1.f + erff(a1 * 0.70710678118654752f)) * a2;
    gp[(size_t)r * WID] = f2bf(g);
    #pragma unroll
    for (int j = 0; j < 3; ++j) {
      A[0][j] = A[1][j];  A[1][j] = A[2][j];
      B2[0][j] = B2[1][j]; B2[1][j] = B2[2][j];
    }
  }
}

// ------- tiny: transpose w_out [64][170] -> wT [170][64] -------
__global__ void k_wt(const float* __restrict__ w_out, float* __restrict__ wT) {
  const int i = blockIdx.x * 256 + threadIdx.x;
  if (i < HID * 64) {
    const int c = i >> 6, d = i & 63;
    wT[c * 64 + d] = w_out[d * HID + c];
  }
}

// ------- K3b: project_out (170 -> 64), thread-per-pixel, acc[64] -------
__global__ __launch_bounds__(256) void k_projout(const u16* __restrict__ gbuf,
                                                 const float* __restrict__ wT,
                                                 float* __restrict__ out, int hb) {
  const int t = blockIdx.x * 256 + threadIdx.x;
  const int b = t >> 15;
  const int p = t & 32767;
  const u16* g = gbuf + (size_t)b * HID * BAND * WID + p;
  float acc[64];
  #pragma unroll
  for (int d = 0; d < 64; ++d) acc[d] = 0.f;
  for (int c = 0; c < HID; ++c) {
    const float gv = bf2f(g[(size_t)c * BAND * WID]);
    const float* wr = wT + c * 64;
    #pragma unroll
    for (int d = 0; d < 64; ++d) acc[d] += wr[d] * gv;
  }
  float* op = out + (size_t)b * 64 * HW + (size_t)hb * WID + p;
  #pragma unroll
  for (int d = 0; d < 64; ++d) op[(size_t)d * HW] = acc[d];
}

extern "C" void kernel_launch(void* const* d_in, const int* in_sizes, int n_in,
                              void* d_out, int out_size, void* d_ws, size_t ws_size,
                              hipStream_t stream) {
  const float* x     = (const float*)d_in[0];
  const float* w_in  = (const float*)d_in[1];
  const float* w_dw  = (const float*)d_in[2];
  const float* fw    = (const float*)d_in[3];
  const float* w_out = (const float*)d_in[4];
  float* out = (float*)d_out;

  char* ws = (char*)d_ws;
  u16* mid    = (u16*)ws;                                  // 178,257,920 B
  u16* gbuf   = (u16*)(ws + 178257920);                    // 44,564,480 B
  u16* xt     = (u16*)(ws + 178257920);                    // aliases gbuf (used before it)
  float* wT   = (float*)(ws + 178257920 + 44564480);       // 43,520 B
  u16* mfrag  = (u16*)(ws + 178257920 + 44564480 + 43520); // 2,785,280 B
  u16* wfrag  = (u16*)(ws + 178257920 + 44564480 + 43520 + 2785280); // 45,056 B

  k_wt<<<(HID*64 + 255)/256, 256, 0, stream>>>(w_out, wT);
  k_wfrag<<<1, 256, 0, stream>>>(w_in, wfrag);
  k_mfrag<<<C2, 256, 0, stream>>>(fw, mfrag);
  k_xt<<<NB*256, 256, 0, stream>>>(x, xt);
  k_projin2<<<NB*256, 256, 0, stream>>>(xt, wfrag, mid);
  k_pconv2<<<NB*C2*2, 256, 0, stream>>>(mid, mfrag);
  for (int sb = 0; sb < 2; ++sb) {
    const int hb = sb * BAND;
    k_gate<<<NB*HID*8, 256, 0, stream>>>(mid, w_dw, gbuf, hb);
    k_projout<<<(NB*BAND*WID)/256, 256, 0, stream>>>(gbuf, wT, out, hb);
  }
}

// Round 5
// 372.690 us; speedup vs baseline: 5.0897x; 1.0101x over previous
//
#include <hip/hip_runtime.h>
#include <hip/hip_bf16.h>

#define C2 340
#define HID 170
#define NB 4
#define HGT 256
#define WID 256
#define HW (HGT*WID)
#define BAND 128

typedef unsigned short u16;
typedef unsigned int u32;
typedef float f32x4 __attribute__((ext_vector_type(4)));
typedef short s16x8 __attribute__((ext_vector_type(8)));

__device__ __forceinline__ float bf2f(u16 u) {
  union { u32 i; float f; } v; v.i = ((u32)u) << 16; return v.f;
}
__device__ __forceinline__ u16 f2bf(float f) {
  union { float f; u32 i; } v; v.f = f;
  u32 x = v.i;
  return (u16)((x + 0x7fffu + ((x >> 16) & 1u)) >> 16);
}

__device__ const float COSTAB[8] = {1.f, 0.70710678118654752f, 0.f, -0.70710678118654752f,
                                    -1.f, -0.70710678118654752f, 0.f, 0.70710678118654752f};

// ------- prepass: transpose x [b][64][HW] f32 -> xt [b][pix][64] bf16 -------
__global__ __launch_bounds__(256) void k_xt(const float* __restrict__ x,
                                            u16* __restrict__ xt) {
  const int b = blockIdx.x >> 8;
  const int pix = ((blockIdx.x & 255) << 8) + threadIdx.x;
  const float* xp = x + (size_t)b * 64 * HW + pix;
  float v[64];
  #pragma unroll
  for (int c = 0; c < 64; ++c) v[c] = xp[(size_t)c * HW];
  u32 pk[32];
  #pragma unroll
  for (int i = 0; i < 32; ++i)
    pk[i] = (u32)f2bf(v[2*i]) | ((u32)f2bf(v[2*i+1]) << 16);
  uint4* op = (uint4*)(xt + ((size_t)b * 65536 + pix) * 64);
  #pragma unroll
  for (int i = 0; i < 8; ++i)
    op[i] = make_uint4(pk[4*i], pk[4*i+1], pk[4*i+2], pk[4*i+3]);
}

// ------- prepass: W [340][64] f32 -> bf16 A-fragments, padded to 352 rows -------
__global__ __launch_bounds__(256) void k_wfrag(const float* __restrict__ w_in,
                                               u16* __restrict__ wf) {
  for (int e = threadIdx.x; e < 22*2*64*8; e += 256) {
    const int r = e & 7;
    const int l = (e >> 3) & 63;
    const int ts = e >> 9;
    const int s = ts & 1, t = ts >> 1;
    const int m = t*16 + (l & 15);
    const int k = s*32 + ((l >> 4) << 3) + r;
    wf[e] = (m < C2) ? f2bf(w_in[m*64 + k]) : (u16)0;
  }
}

// ---------------- K1: project_in (64 -> 340) via MFMA, LDS-transposed stores ----------------
__global__ __launch_bounds__(256) void k_projin2(const u16* __restrict__ xt,
                                                 const u16* __restrict__ wf,
                                                 u16* __restrict__ mid) {
  __shared__ __align__(16) u16 aw[22*2*64*8];     // 45056 B
  __shared__ __align__(16) u16 st[16][264];       // 8448 B epilogue tile
  for (int i = threadIdx.x; i < 22*2*64; i += 256)
    ((uint4*)aw)[i] = ((const uint4*)wf)[i];
  const int b = blockIdx.x >> 8;
  const int pix_blk = (blockIdx.x & 255) << 8;     // 256 px per block
  const int w = threadIdx.x >> 6;
  const int lane = threadIdx.x & 63;
  const int lm = lane & 15, lh = lane >> 4;
  const int pix0 = pix_blk + w*64;

  s16x8 Bf[4][2];                                  // 4 pixel groups x 2 ksteps
  const u16* xp = xt + ((size_t)b * 65536 + pix0) * 64;
  #pragma unroll
  for (int g = 0; g < 4; ++g) {
    const u16* p = xp + (g*16 + lm)*64 + lh*8;
    Bf[g][0] = *(const s16x8*)(p);
    Bf[g][1] = *(const s16x8*)(p + 32);
  }
  u16* mp = mid + (size_t)b * C2 * HW + pix_blk;
  const int ch_rd = threadIdx.x >> 4;              // 0..15 (row for writeout)
  const int seg = threadIdx.x & 15;                // 16 B segment
  for (int t = 0; t < 22; ++t) {
    const s16x8 A0 = *(const s16x8*)(aw + ((t*2 + 0)*64 + lane)*8);
    const s16x8 A1 = *(const s16x8*)(aw + ((t*2 + 1)*64 + lane)*8);
    f32x4 ac[4];
    #pragma unroll
    for (int g = 0; g < 4; ++g) {
      ac[g] = (f32x4){0.f,0.f,0.f,0.f};
      ac[g] = __builtin_amdgcn_mfma_f32_16x16x32_bf16(A0, Bf[g][0], ac[g], 0,0,0);
      ac[g] = __builtin_amdgcn_mfma_f32_16x16x32_bf16(A1, Bf[g][1], ac[g], 0,0,0);
    }
    __syncthreads();                               // st free (prev readers done; t=0: aw staged)
    #pragma unroll
    for (int g = 0; g < 4; ++g)
      #pragma unroll
      for (int r = 0; r < 4; ++r)
        st[lh*4 + r][w*64 + g*16 + lm] = f2bf(ac[g][r]);
    __syncthreads();
    const int ch = t*16 + ch_rd;
    if (ch < C2) {
      u16* dst = mp + (size_t)ch * HW + seg*16;
      *(uint4*)dst       = *(const uint4*)&st[ch_rd][seg*16];
      *(uint4*)(dst + 8) = *(const uint4*)&st[ch_rd][seg*16 + 8];
    }
  }
}

// ------- prepass: build per-channel conv matrix in MFMA B-fragment order -------
__global__ __launch_bounds__(256) void k_mfrag(const float* __restrict__ fw,
                                               u16* __restrict__ mf) {
  __shared__ float kern[64];
  const int c = blockIdx.x;
  if (threadIdx.x < 64) {
    const int a = threadIdx.x >> 3, bb = threadIdx.x & 7;
    float acc = 0.f;
    for (int u = 0; u < 8; ++u)
      for (int v = 0; v < 8; ++v) {
        const float wv = (v <= 4) ? fw[c*40 + u*5 + v]
                                  : fw[c*40 + ((8-u)&7)*5 + (8-v)];
        acc += wv * COSTAB[(u*a + v*bb) & 7];
      }
    kern[threadIdx.x] = acc * (1.f/64.f);
  }
  __syncthreads();
  #pragma unroll
  for (int q = 0; q < 16; ++q) {
    const int e = q * 256 + threadIdx.x;
    const int r = e & 7;
    const int l = (e >> 3) & 63;
    const int sb = e >> 9;
    const int s = sb & 1, nblk = sb >> 1;
    const int k = s*32 + ((l >> 4) << 3) + r;
    const int a = k >> 3, bcol = k & 7;
    const int n = nblk*16 + (l & 15);
    const int i = n >> 3, j = n & 7;
    mf[(size_t)c * 4096 + e] = f2bf(kern[(((i - a) & 7) << 3) + ((j - bcol) & 7)]);
  }
}

// ------- K2: per-channel 8x8 circular conv as MFMA GEMM, in place, LDS epilogue -------
__global__ __launch_bounds__(256) void k_pconv2(u16* __restrict__ mid,
                                                const u16* __restrict__ mf) {
  __shared__ __align__(16) u16 st[16][264];       // 16 rows x 256 cols region tile
  const int gid = blockIdx.x;
  const int half = gid & 1;
  const int bc = gid >> 1;
  const int c = bc % C2;
  const int lane = threadIdx.x & 63;
  const int w = threadIdx.x >> 6;
  u16* chan = mid + (size_t)bc * HW;

  s16x8 Bf[4][2];
  const u16* mfc = mf + (size_t)c * 4096;
  #pragma unroll
  for (int nb = 0; nb < 4; ++nb)
    #pragma unroll
    for (int s = 0; s < 2; ++s)
      Bf[nb][s] = *(const s16x8*)(mfc + ((nb*2 + s)*64 + lane)*8);

  const int lm = lane & 15, lh = lane >> 4;
  const int rr = threadIdx.x >> 4;                 // writeout row 0..15
  const int seg = threadIdx.x & 15;
  for (int it = 0; it < 8; ++it) {
    const int pg = half*512 + (it*4 + w)*16;       // 16-patch group base
    const int py = pg >> 5, px0 = pg & 31;
    const u16* aptr = chan + (size_t)(py*8 + lh)*WID + (px0 + lm)*8;
    const s16x8 A0 = *(const s16x8*)(aptr);
    const s16x8 A1 = *(const s16x8*)(aptr + 4*WID);
    f32x4 ac0 = {0.f,0.f,0.f,0.f}, ac1 = {0.f,0.f,0.f,0.f};
    f32x4 ac2 = {0.f,0.f,0.f,0.f}, ac3 = {0.f,0.f,0.f,0.f};
    ac0 = __builtin_amdgcn_mfma_f32_16x16x32_bf16(A0, Bf[0][0], ac0, 0,0,0);
    ac0 = __builtin_amdgcn_mfma_f32_16x16x32_bf16(A1, Bf[0][1], ac0, 0,0,0);
    ac1 = __builtin_amdgcn_mfma_f32_16x16x32_bf16(A0, Bf[1][0], ac1, 0,0,0);
    ac1 = __builtin_amdgcn_mfma_f32_16x16x32_bf16(A1, Bf[1][1], ac1, 0,0,0);
    ac2 = __builtin_amdgcn_mfma_f32_16x16x32_bf16(A0, Bf[2][0], ac2, 0,0,0);
    ac2 = __builtin_amdgcn_mfma_f32_16x16x32_bf16(A1, Bf[2][1], ac2, 0,0,0);
    ac3 = __builtin_amdgcn_mfma_f32_16x16x32_bf16(A0, Bf[3][0], ac3, 0,0,0);
    ac3 = __builtin_amdgcn_mfma_f32_16x16x32_bf16(A1, Bf[3][1], ac3, 0,0,0);
    // stage D to LDS: patch p = (w>>1)*32 + (w&1)*16 + lh*4 + r (within 2-patch-row region)
    //                 pixel t = nblk*16 + lm -> i = t>>3, j = t&7
    __syncthreads();
    const int colbase = ((w & 1)*16 + lh*4)*8 + (lm & 7);
    const int rowbase = (w >> 1)*8 + (lm >> 3);    // + nblk*2
    #pragma unroll
    for (int r = 0; r < 4; ++r) {
      st[rowbase + 0][colbase + r*8] = f2bf(ac0[r]);
      st[rowbase + 2][colbase + r*8] = f2bf(ac1[r]);
      st[rowbase + 4][colbase + r*8] = f2bf(ac2[r]);
      st[rowbase + 6][colbase + r*8] = f2bf(ac3[r]);
    }
    __syncthreads();
    const int row0 = half*128 + it*16;             // region rows row0..row0+15
    u16* dst = chan + (size_t)(row0 + rr)*WID + seg*16;
    *(uint4*)dst       = *(const uint4*)&st[rr][seg*16];
    *(uint4*)(dst + 8) = *(const uint4*)&st[rr][seg*16 + 8];
  }
}

// ------- K3a: depthwise 3x3 + exact GELU gate, band-wise, coalesced -------
__global__ __launch_bounds__(256) void k_gate(const u16* __restrict__ mid,
                                              const float* __restrict__ w_dw,
                                              u16* __restrict__ gbuf, int hb) {
  __shared__ __align__(16) u16 sh[2][18][272];
  const int s  = blockIdx.x & 7;
  const int bc = blockIdx.x >> 3;
  const int c  = bc % HID, b = bc / HID;
  const int h0 = hb + s * 16;

  u32* shw = (u32*)sh;
  for (int i = threadIdx.x; i < 2*18*136; i += 256) shw[i] = 0;
  __syncthreads();
  for (int i = threadIdx.x; i < 2*18*32; i += 256) {
    const int k = i & 31;
    const int r = (i >> 5) % 18;
    const int ch2 = i / (18*32);
    const int h = h0 + r - 1;
    if (h >= 0 && h < HGT) {
      const u16* src = mid + ((size_t)(b*C2 + c + ch2*HID)) * HW + (size_t)h * WID + k*8;
      *(uint4*)&sh[ch2][r][8 + k*8] = *(const uint4*)src;
    }
  }
  __syncthreads();

  const int cc = threadIdx.x;
  const float* wd1 = w_dw + c * 9;
  const float* wd2 = w_dw + (c + HID) * 9;
  u16* gp = gbuf + (((size_t)(b*HID + c)) * BAND + (h0 - hb)) * WID + cc;

  float A[3][3], B2[3][3];
  #pragma unroll
  for (int ri = 0; ri < 2; ++ri)
    #pragma unroll
    for (int j = 0; j < 3; ++j) {
      A[ri][j]  = bf2f(sh[0][ri][7 + cc + j]);
      B2[ri][j] = bf2f(sh[1][ri][7 + cc + j]);
    }
  #pragma unroll 4
  for (int r = 0; r < 16; ++r) {
    #pragma unroll
    for (int j = 0; j < 3; ++j) {
      A[2][j]  = bf2f(sh[0][r+2][7 + cc + j]);
      B2[2][j] = bf2f(sh[1][r+2][7 + cc + j]);
    }
    float a1 = 0.f, a2 = 0.f;
    #pragma unroll
    for (int ri = 0; ri < 3; ++ri)
      #pragma unroll
      for (int j = 0; j < 3; ++j) {
        a1 += wd1[ri*3 + j] * A[ri][j];
        a2 += wd2[ri*3 + j] * B2[ri][j];
      }
    const float g = 0.5f * a1 * (1.f + erff(a1 * 0.70710678118654752f)) * a2;
    gp[(size_t)r * WID] = f2bf(g);
    #pragma unroll
    for (int j = 0; j < 3; ++j) {
      A[0][j] = A[1][j];  A[1][j] = A[2][j];
      B2[0][j] = B2[1][j]; B2[1][j] = B2[2][j];
    }
  }
}

// ------- tiny: transpose w_out [64][170] -> wT [170][64] -------
__global__ void k_wt(const float* __restrict__ w_out, float* __restrict__ wT) {
  const int i = blockIdx.x * 256 + threadIdx.x;
  if (i < HID * 64) {
    const int c = i >> 6, d = i & 63;
    wT[c * 64 + d] = w_out[d * HID + c];
  }
}

// ------- K3b: project_out (170 -> 64), thread-per-pixel, acc[64] -------
__global__ __launch_bounds__(256) void k_projout(const u16* __restrict__ gbuf,
                                                 const float* __restrict__ wT,
                                                 float* __restrict__ out, int hb) {
  const int t = blockIdx.x * 256 + threadIdx.x;
  const int b = t >> 15;
  const int p = t & 32767;
  const u16* g = gbuf + (size_t)b * HID * BAND * WID + p;
  float acc[64];
  #pragma unroll
  for (int d = 0; d < 64; ++d) acc[d] = 0.f;
  for (int c = 0; c < HID; ++c) {
    const float gv = bf2f(g[(size_t)c * BAND * WID]);
    const float* wr = wT + c * 64;
    #pragma unroll
    for (int d = 0; d < 64; ++d) acc[d] += wr[d] * gv;
  }
  float* op = out + (size_t)b * 64 * HW + (size_t)hb * WID + p;
  #pragma unroll
  for (int d = 0; d < 64; ++d) op[(size_t)d * HW] = acc[d];
}

extern "C" void kernel_launch(void* const* d_in, const int* in_sizes, int n_in,
                              void* d_out, int out_size, void* d_ws, size_t ws_size,
                              hipStream_t stream) {
  const float* x     = (const float*)d_in[0];
  const float* w_in  = (const float*)d_in[1];
  const float* w_dw  = (const float*)d_in[2];
  const float* fw    = (const float*)d_in[3];
  const float* w_out = (const float*)d_in[4];
  float* out = (float*)d_out;

  char* ws = (char*)d_ws;
  u16* mid    = (u16*)ws;                                  // 178,257,920 B
  u16* gbuf   = (u16*)(ws + 178257920);                    // 44,564,480 B
  u16* xt     = (u16*)(ws + 178257920);                    // aliases gbuf (used before it)
  float* wT   = (float*)(ws + 178257920 + 44564480);       // 43,520 B
  u16* mfrag  = (u16*)(ws + 178257920 + 44564480 + 43520); // 2,785,280 B
  u16* wfrag  = (u16*)(ws + 178257920 + 44564480 + 43520 + 2785280); // 45,056 B

  k_wt<<<(HID*64 + 255)/256, 256, 0, stream>>>(w_out, wT);
  k_wfrag<<<1, 256, 0, stream>>>(w_in, wfrag);
  k_mfrag<<<C2, 256, 0, stream>>>(fw, mfrag);
  k_xt<<<NB*256, 256, 0, stream>>>(x, xt);
  k_projin2<<<NB*256, 256, 0, stream>>>(xt, wfrag, mid);
  k_pconv2<<<NB*C2*2, 256, 0, stream>>>(mid, mfrag);
  for (int sb = 0; sb < 2; ++sb) {
    const int hb = sb * BAND;
    k_gate<<<NB*HID*8, 256, 0, stream>>>(mid, w_dw, gbuf, hb);
    k_projout<<<(NB*BAND*WID)/256, 256, 0, stream>>>(gbuf, wT, out, hb);
  }
}

// Round 7
// 307.503 us; speedup vs baseline: 6.1686x; 1.2120x over previous
//
#include <hip/hip_runtime.h>
#include <hip/hip_bf16.h>

#define C2 340
#define HID 170
#define NB 4
#define HGT 256
#define WID 256
#define HW (HGT*WID)
#define BAND 128

typedef unsigned short u16;
typedef unsigned int u32;
typedef float f32x4 __attribute__((ext_vector_type(4)));
typedef short s16x8 __attribute__((ext_vector_type(8)));

__device__ __forceinline__ float bf2f(u16 u) {
  union { u32 i; float f; } v; v.i = ((u32)u) << 16; return v.f;
}
__device__ __forceinline__ u16 f2bf(float f) {
  union { float f; u32 i; } v; v.f = f;
  u32 x = v.i;
  return (u16)((x + 0x7fffu + ((x >> 16) & 1u)) >> 16);
}

__device__ const float COSTAB[8] = {1.f, 0.70710678118654752f, 0.f, -0.70710678118654752f,
                                    -1.f, -0.70710678118654752f, 0.f, 0.70710678118654752f};

// ------- prepass: transpose x [b][64][HW] f32 -> xt [b][pix][64] bf16 -------
__global__ __launch_bounds__(256) void k_xt(const float* __restrict__ x,
                                            u16* __restrict__ xt) {
  const int b = blockIdx.x >> 8;
  const int pix = ((blockIdx.x & 255) << 8) + threadIdx.x;
  const float* xp = x + (size_t)b * 64 * HW + pix;
  float v[64];
  #pragma unroll
  for (int c = 0; c < 64; ++c) v[c] = xp[(size_t)c * HW];
  u32 pk[32];
  #pragma unroll
  for (int i = 0; i < 32; ++i)
    pk[i] = (u32)f2bf(v[2*i]) | ((u32)f2bf(v[2*i+1]) << 16);
  uint4* op = (uint4*)(xt + ((size_t)b * 65536 + pix) * 64);
  #pragma unroll
  for (int i = 0; i < 8; ++i)
    op[i] = make_uint4(pk[4*i], pk[4*i+1], pk[4*i+2], pk[4*i+3]);
}

// ------- prepass: W_in [340][64] f32 -> bf16 A-fragments, padded to 352 rows -------
__global__ __launch_bounds__(256) void k_wfrag(const float* __restrict__ w_in,
                                               u16* __restrict__ wf) {
  for (int e = threadIdx.x; e < 22*2*64*8; e += 256) {
    const int r = e & 7;
    const int l = (e >> 3) & 63;
    const int ts = e >> 9;
    const int s = ts & 1, t = ts >> 1;
    const int m = t*16 + (l & 15);
    const int k = s*32 + ((l >> 4) << 3) + r;
    wf[e] = (m < C2) ? f2bf(w_in[m*64 + k]) : (u16)0;
  }
}

// ------- prepass: w_out [64][170] f32 -> bf16 A-fragments, K padded to 192 -------
__global__ __launch_bounds__(256) void k_wofrag(const float* __restrict__ w_out,
                                                u16* __restrict__ wof) {
  for (int e = threadIdx.x; e < 4*6*64*8; e += 256) {
    const int r = e & 7;
    const int l = (e >> 3) & 63;
    const int mk = e >> 9;
    const int kc = mk % 6, mt = mk / 6;
    const int m = mt*16 + (l & 15);
    const int k = kc*32 + ((l >> 4) << 3) + r;
    wof[e] = (k < HID) ? f2bf(w_out[m*HID + k]) : (u16)0;
  }
}

// ---------------- K1: project_in (64 -> 340) via MFMA, LDS-transposed stores ----------------
__global__ __launch_bounds__(256) void k_projin2(const u16* __restrict__ xt,
                                                 const u16* __restrict__ wf,
                                                 u16* __restrict__ mid) {
  __shared__ __align__(16) u16 aw[22*2*64*8];     // 45056 B
  __shared__ __align__(16) u16 st[16][264];       // 8448 B epilogue tile
  for (int i = threadIdx.x; i < 22*2*64; i += 256)
    ((uint4*)aw)[i] = ((const uint4*)wf)[i];
  const int b = blockIdx.x >> 8;
  const int pix_blk = (blockIdx.x & 255) << 8;     // 256 px per block
  const int w = threadIdx.x >> 6;
  const int lane = threadIdx.x & 63;
  const int lm = lane & 15, lh = lane >> 4;
  const int pix0 = pix_blk + w*64;

  s16x8 Bf[4][2];                                  // 4 pixel groups x 2 ksteps
  const u16* xp = xt + ((size_t)b * 65536 + pix0) * 64;
  #pragma unroll
  for (int g = 0; g < 4; ++g) {
    const u16* p = xp + (g*16 + lm)*64 + lh*8;
    Bf[g][0] = *(const s16x8*)(p);
    Bf[g][1] = *(const s16x8*)(p + 32);
  }
  u16* mp = mid + (size_t)b * C2 * HW + pix_blk;
  const int ch_rd = threadIdx.x >> 4;              // 0..15 (row for writeout)
  const int seg = threadIdx.x & 15;                // 16 B segment
  for (int t = 0; t < 22; ++t) {
    const s16x8 A0 = *(const s16x8*)(aw + ((t*2 + 0)*64 + lane)*8);
    const s16x8 A1 = *(const s16x8*)(aw + ((t*2 + 1)*64 + lane)*8);
    f32x4 ac[4];
    #pragma unroll
    for (int g = 0; g < 4; ++g) {
      ac[g] = (f32x4){0.f,0.f,0.f,0.f};
      ac[g] = __builtin_amdgcn_mfma_f32_16x16x32_bf16(A0, Bf[g][0], ac[g], 0,0,0);
      ac[g] = __builtin_amdgcn_mfma_f32_16x16x32_bf16(A1, Bf[g][1], ac[g], 0,0,0);
    }
    __syncthreads();                               // st free (prev readers done; t=0: aw staged)
    #pragma unroll
    for (int g = 0; g < 4; ++g)
      #pragma unroll
      for (int r = 0; r < 4; ++r)
        st[lh*4 + r][w*64 + g*16 + lm] = f2bf(ac[g][r]);
    __syncthreads();
    const int ch = t*16 + ch_rd;
    if (ch < C2) {
      u16* dst = mp + (size_t)ch * HW + seg*16;
      *(uint4*)dst       = *(const uint4*)&st[ch_rd][seg*16];
      *(uint4*)(dst + 8) = *(const uint4*)&st[ch_rd][seg*16 + 8];
    }
  }
}

// ------- prepass: build per-channel conv matrix in MFMA B-fragment order -------
__global__ __launch_bounds__(256) void k_mfrag(const float* __restrict__ fw,
                                               u16* __restrict__ mf) {
  __shared__ float kern[64];
  const int c = blockIdx.x;
  if (threadIdx.x < 64) {
    const int a = threadIdx.x >> 3, bb = threadIdx.x & 7;
    float acc = 0.f;
    for (int u = 0; u < 8; ++u)
      for (int v = 0; v < 8; ++v) {
        const float wv = (v <= 4) ? fw[c*40 + u*5 + v]
                                  : fw[c*40 + ((8-u)&7)*5 + (8-v)];
        acc += wv * COSTAB[(u*a + v*bb) & 7];
      }
    kern[threadIdx.x] = acc * (1.f/64.f);
  }
  __syncthreads();
  #pragma unroll
  for (int q = 0; q < 16; ++q) {
    const int e = q * 256 + threadIdx.x;
    const int r = e & 7;
    const int l = (e >> 3) & 63;
    const int sb = e >> 9;
    const int s = sb & 1, nblk = sb >> 1;
    const int k = s*32 + ((l >> 4) << 3) + r;
    const int a = k >> 3, bcol = k & 7;
    const int n = nblk*16 + (l & 15);
    const int i = n >> 3, j = n & 7;
    mf[(size_t)c * 4096 + e] = f2bf(kern[(((i - a) & 7) << 3) + ((j - bcol) & 7)]);
  }
}

// ------- K2: per-channel 8x8 circular conv as MFMA GEMM, in place, LDS epilogue -------
__global__ __launch_bounds__(256) void k_pconv2(u16* __restrict__ mid,
                                                const u16* __restrict__ mf) {
  __shared__ __align__(16) u16 st[16][264];       // 16 rows x 256 cols region tile
  const int gid = blockIdx.x;
  const int half = gid & 1;
  const int bc = gid >> 1;
  const int c = bc % C2;
  const int lane = threadIdx.x & 63;
  const int w = threadIdx.x >> 6;
  u16* chan = mid + (size_t)bc * HW;

  s16x8 Bf[4][2];
  const u16* mfc = mf + (size_t)c * 4096;
  #pragma unroll
  for (int nb = 0; nb < 4; ++nb)
    #pragma unroll
    for (int s = 0; s < 2; ++s)
      Bf[nb][s] = *(const s16x8*)(mfc + ((nb*2 + s)*64 + lane)*8);

  const int lm = lane & 15, lh = lane >> 4;
  const int rr = threadIdx.x >> 4;                 // writeout row 0..15
  const int seg = threadIdx.x & 15;
  for (int it = 0; it < 8; ++it) {
    const int pg = half*512 + (it*4 + w)*16;       // 16-patch group base
    const int py = pg >> 5, px0 = pg & 31;
    const u16* aptr = chan + (size_t)(py*8 + lh)*WID + (px0 + lm)*8;
    const s16x8 A0 = *(const s16x8*)(aptr);
    const s16x8 A1 = *(const s16x8*)(aptr + 4*WID);
    f32x4 ac0 = {0.f,0.f,0.f,0.f}, ac1 = {0.f,0.f,0.f,0.f};
    f32x4 ac2 = {0.f,0.f,0.f,0.f}, ac3 = {0.f,0.f,0.f,0.f};
    ac0 = __builtin_amdgcn_mfma_f32_16x16x32_bf16(A0, Bf[0][0], ac0, 0,0,0);
    ac0 = __builtin_amdgcn_mfma_f32_16x16x32_bf16(A1, Bf[0][1], ac0, 0,0,0);
    ac1 = __builtin_amdgcn_mfma_f32_16x16x32_bf16(A0, Bf[1][0], ac1, 0,0,0);
    ac1 = __builtin_amdgcn_mfma_f32_16x16x32_bf16(A1, Bf[1][1], ac1, 0,0,0);
    ac2 = __builtin_amdgcn_mfma_f32_16x16x32_bf16(A0, Bf[2][0], ac2, 0,0,0);
    ac2 = __builtin_amdgcn_mfma_f32_16x16x32_bf16(A1, Bf[2][1], ac2, 0,0,0);
    ac3 = __builtin_amdgcn_mfma_f32_16x16x32_bf16(A0, Bf[3][0], ac3, 0,0,0);
    ac3 = __builtin_amdgcn_mfma_f32_16x16x32_bf16(A1, Bf[3][1], ac3, 0,0,0);
    __syncthreads();
    const int colbase = ((w & 1)*16 + lh*4)*8 + (lm & 7);
    const int rowbase = (w >> 1)*8 + (lm >> 3);    // + nblk*2
    #pragma unroll
    for (int r = 0; r < 4; ++r) {
      st[rowbase + 0][colbase + r*8] = f2bf(ac0[r]);
      st[rowbase + 2][colbase + r*8] = f2bf(ac1[r]);
      st[rowbase + 4][colbase + r*8] = f2bf(ac2[r]);
      st[rowbase + 6][colbase + r*8] = f2bf(ac3[r]);
    }
    __syncthreads();
    const int row0 = half*128 + it*16;             // region rows row0..row0+15
    u16* dst = chan + (size_t)(row0 + rr)*WID + seg*16;
    *(uint4*)dst       = *(const uint4*)&st[rr][seg*16];
    *(uint4*)(dst + 8) = *(const uint4*)&st[rr][seg*16 + 8];
  }
}

// ------- K3a: depthwise 3x3 + exact GELU gate, band-wise, coalesced -------
__global__ __launch_bounds__(256) void k_gate(const u16* __restrict__ mid,
                                              const float* __restrict__ w_dw,
                                              u16* __restrict__ gbuf, int hb) {
  __shared__ __align__(16) u16 sh[2][18][272];
  const int s  = blockIdx.x & 7;
  const int bc = blockIdx.x >> 3;
  const int c  = bc % HID, b = bc / HID;
  const int h0 = hb + s * 16;

  u32* shw = (u32*)sh;
  for (int i = threadIdx.x; i < 2*18*136; i += 256) shw[i] = 0;
  __syncthreads();
  for (int i = threadIdx.x; i < 2*18*32; i += 256) {
    const int k = i & 31;
    const int r = (i >> 5) % 18;
    const int ch2 = i / (18*32);
    const int h = h0 + r - 1;
    if (h >= 0 && h < HGT) {
      const u16* src = mid + ((size_t)(b*C2 + c + ch2*HID)) * HW + (size_t)h * WID + k*8;
      *(uint4*)&sh[ch2][r][8 + k*8] = *(const uint4*)src;
    }
  }
  __syncthreads();

  const int cc = threadIdx.x;
  const float* wd1 = w_dw + c * 9;
  const float* wd2 = w_dw + (c + HID) * 9;
  u16* gp = gbuf + (((size_t)(b*HID + c)) * BAND + (h0 - hb)) * WID + cc;

  float A[3][3], B2[3][3];
  #pragma unroll
  for (int ri = 0; ri < 2; ++ri)
    #pragma unroll
    for (int j = 0; j < 3; ++j) {
      A[ri][j]  = bf2f(sh[0][ri][7 + cc + j]);
      B2[ri][j] = bf2f(sh[1][ri][7 + cc + j]);
    }
  #pragma unroll 4
  for (int r = 0; r < 16; ++r) {
    #pragma unroll
    for (int j = 0; j < 3; ++j) {
      A[2][j]  = bf2f(sh[0][r+2][7 + cc + j]);
      B2[2][j] = bf2f(sh[1][r+2][7 + cc + j]);
    }
    float a1 = 0.f, a2 = 0.f;
    #pragma unroll
    for (int ri = 0; ri < 3; ++ri)
      #pragma unroll
      for (int j = 0; j < 3; ++j) {
        a1 += wd1[ri*3 + j] * A[ri][j];
        a2 += wd2[ri*3 + j] * B2[ri][j];
      }
    const float g = 0.5f * a1 * (1.f + erff(a1 * 0.70710678118654752f)) * a2;
    gp[(size_t)r * WID] = f2bf(g);
    #pragma unroll
    for (int j = 0; j < 3; ++j) {
      A[0][j] = A[1][j];  A[1][j] = A[2][j];
      B2[0][j] = B2[1][j]; B2[1][j] = B2[2][j];
    }
  }
}

// ------- K3b: project_out (170 -> 64) via MFMA -------
// out[64][px] = W[64 x 192pad] * gate[170][px]; block = 256 px (one band row)
__global__ __launch_bounds__(256) void k_projout2(const u16* __restrict__ gbuf,
                                                  const u16* __restrict__ wof,
                                                  float* __restrict__ out, int hb) {
  const int b = blockIdx.x >> 7;                  // 128 blocks (rows) per batch
  const int p0 = (blockIdx.x & 127) << 8;
  const int w = threadIdx.x >> 6;
  const int lane = threadIdx.x & 63;
  const int lm = lane & 15, lh = lane >> 4;
  const size_t BW = (size_t)BAND * WID;
  const u16* gb = gbuf + (size_t)b * HID * BW + p0 + w*64 + lm;

  f32x4 acc[4][4];
  #pragma unroll
  for (int mt = 0; mt < 4; ++mt)
    #pragma unroll
    for (int ng = 0; ng < 4; ++ng)
      acc[mt][ng] = (f32x4){0.f,0.f,0.f,0.f};

  #pragma unroll
  for (int kc = 0; kc < 6; ++kc) {
    s16x8 A[4];
    #pragma unroll
    for (int mt = 0; mt < 4; ++mt)
      A[mt] = *(const s16x8*)(wof + ((mt*6 + kc)*64 + lane)*8);
    #pragma unroll
    for (int ng = 0; ng < 4; ++ng) {
      s16x8 Bf;
      #pragma unroll
      for (int r = 0; r < 8; ++r) {
        int c = kc*32 + lh*8 + r;
        if (kc == 5) c = min(c, HID - 1);          // A zero-padded for k>=170
        Bf[r] = (short)gb[(size_t)c * BW + ng*16];
      }
      #pragma unroll
      for (int mt = 0; mt < 4; ++mt)
        acc[mt][ng] = __builtin_amdgcn_mfma_f32_16x16x32_bf16(A[mt], Bf, acc[mt][ng], 0,0,0);
    }
  }
  float* ob = out + (size_t)b * 64 * HW + (size_t)hb * WID + p0 + w*64 + lm;
  #pragma unroll
  for (int mt = 0; mt < 4; ++mt)
    #pragma unroll
    for (int ng = 0; ng < 4; ++ng)
      #pragma unroll
      for (int r = 0; r < 4; ++r)
        ob[(size_t)(mt*16 + lh*4 + r) * HW + ng*16] = acc[mt][ng][r];
}

extern "C" void kernel_launch(void* const* d_in, const int* in_sizes, int n_in,
                              void* d_out, int out_size, void* d_ws, size_t ws_size,
                              hipStream_t stream) {
  const float* x     = (const float*)d_in[0];
  const float* w_in  = (const float*)d_in[1];
  const float* w_dw  = (const float*)d_in[2];
  const float* fw    = (const float*)d_in[3];
  const float* w_out = (const float*)d_in[4];
  float* out = (float*)d_out;

  char* ws = (char*)d_ws;
  u16* mid    = (u16*)ws;                                  // 178,257,920 B
  u16* gbuf   = (u16*)(ws + 178257920);                    // 44,564,480 B
  u16* xt     = (u16*)(ws + 178257920);                    // aliases gbuf (used before it)
  u16* wof    = (u16*)(ws + 178257920 + 44564480);         // 24,576 B (w_out A-frags)
  u16* mfrag  = (u16*)(ws + 178257920 + 44564480 + 43520); // 2,785,280 B
  u16* wfrag  = (u16*)(ws + 178257920 + 44564480 + 43520 + 2785280); // 45,056 B

  k_wofrag<<<1, 256, 0, stream>>>(w_out, wof);
  k_wfrag<<<1, 256, 0, stream>>>(w_in, wfrag);
  k_mfrag<<<C2, 256, 0, stream>>>(fw, mfrag);
  k_xt<<<NB*256, 256, 0, stream>>>(x, xt);
  k_projin2<<<NB*256, 256, 0, stream>>>(xt, wfrag, mid);
  k_pconv2<<<NB*C2*2, 256, 0, stream>>>(mid, mfrag);
  for (int sb = 0; sb < 2; ++sb) {
    const int hb = sb * BAND;
    k_gate<<<NB*HID*8, 256, 0, stream>>>(mid, w_dw, gbuf, hb);
    k_projout2<<<NB*BAND, 256, 0, stream>>>(gbuf, wof, out, hb);   // 256 px per block
  }
}